// Round 11
// baseline (508.636 us; speedup 1.0000x reference)
//
#include <hip/hip_runtime.h>
#include <math.h>

#define WIDTH 256
typedef unsigned short u16;
typedef unsigned int u32;
typedef __attribute__((ext_vector_type(4))) float f32x4;
typedef __attribute__((ext_vector_type(8))) short bf16x8;

__device__ __forceinline__ float gelu_exact(float v) {
    return 0.5f * v * (1.0f + erff(v * 0.70710678118654752f));
}
__device__ __forceinline__ u16 f2b(float x) {   // f32 -> bf16 RTNE
    u32 u = __builtin_bit_cast(u32, x);
    return (u16)((u + 0x7fffu + ((u >> 16) & 1u)) >> 16);
}
__device__ __forceinline__ float b2f_lo(u32 v) {
    return __builtin_bit_cast(float, v << 16);
}
__device__ __forceinline__ float b2f_hi(u32 v) {
    return __builtin_bit_cast(float, v & 0xffff0000u);
}
__device__ __forceinline__ u32 pack2(float a, float b) {
    return (u32)f2b(a) | ((u32)f2b(b) << 16);
}

// ---------------- merged prep: WgT transpose + WfT copy + x->bf16 + hist(rank) ----------------
// deg must be zeroed (hipMemsetAsync) before this kernel.
#define PREP_WG   (4 * 65536)
#define PREP_WF   (256 * 64)
__global__ void k_prep(const float* __restrict__ Wg, const float* __restrict__ Wf,
                       const float* __restrict__ x, const int* __restrict__ col,
                       u16* __restrict__ WgT, u16* __restrict__ WfT,
                       u16* __restrict__ xb, int* __restrict__ deg,
                       int* __restrict__ rank, int total8, int E) {
    int idx = blockIdx.x * blockDim.x + threadIdx.x;
    if (idx < PREP_WG) {
        int l = idx >> 16;
        int k = (idx >> 8) & 255;
        int n = idx & 255;
        WgT[(size_t)l * 65536 + (size_t)n * 256 + k] = f2b(Wg[idx]);
    } else if (idx < PREP_WG + PREP_WF) {
        int j = idx - PREP_WG;
        WfT[j] = f2b(Wf[j]);   // Wf already [n][k]
    } else if (idx < PREP_WG + PREP_WF + total8) {
        int i = idx - (PREP_WG + PREP_WF);
        const float4 v0 = *reinterpret_cast<const float4*>(&x[(size_t)i * 8]);
        const float4 v1 = *reinterpret_cast<const float4*>(&x[(size_t)i * 8 + 4]);
        uint4 o;
        o.x = pack2(v0.x, v0.y);
        o.y = pack2(v0.z, v0.w);
        o.z = pack2(v1.x, v1.y);
        o.w = pack2(v1.z, v1.w);
        *reinterpret_cast<uint4*>(&xb[(size_t)i * 8]) = o;
    } else {
        int i = idx - (PREP_WG + PREP_WF + total8);
        if (i < E) rank[i] = atomicAdd(&deg[col[i]], 1);
    }
}

__global__ __launch_bounds__(256) void k_scan1(const int* __restrict__ deg, int* __restrict__ off,
                                               int* __restrict__ part, float* __restrict__ dis, int N) {
    __shared__ int buf[256];
    const int t = threadIdx.x;
    const int gid = blockIdx.x * 256 + t;
    const int v = (gid < N) ? deg[gid] : 0;
    if (gid < N) dis[gid] = rsqrtf(1.0f + (float)v);
    buf[t] = v;
    __syncthreads();
#pragma unroll
    for (int d = 1; d < 256; d <<= 1) {
        int add = (t >= d) ? buf[t - d] : 0;
        __syncthreads();
        buf[t] += add;
        __syncthreads();
    }
    if (gid < N) off[gid] = buf[t] - v;
    if (t == 255) part[blockIdx.x] = buf[255];
}

// fused scan-of-parts + add-base (each block redundantly scans part[] in LDS)
__global__ __launch_bounds__(256) void k_scan3(int* __restrict__ off, const int* __restrict__ part,
                                               int NB, int N, int E) {
    __shared__ int buf[256];
    const int t = threadIdx.x;
    int v = (t < NB) ? part[t] : 0;
    buf[t] = v;
    __syncthreads();
#pragma unroll
    for (int d = 1; d < 256; d <<= 1) {
        int add = (t >= d) ? buf[t - d] : 0;
        __syncthreads();
        buf[t] += add;
        __syncthreads();
    }
    const int base = (blockIdx.x == 0) ? 0 : buf[blockIdx.x - 1];
    const int gid = blockIdx.x * 256 + t;
    if (gid < N) off[gid] += base;
    if (gid == 0) off[N] = E;
}

// csr entry = (src u16) | (bf16(dis[src]) << 16); position = off[col] + rank (no atomic)
__global__ void k_fill(const int* __restrict__ row, const int* __restrict__ col,
                       const int* __restrict__ rank, const float* __restrict__ dis,
                       const int* __restrict__ off, u32* __restrict__ csr, int E) {
    int i = blockIdx.x * blockDim.x + threadIdx.x;
    if (i < E) {
        const int r = row[i];
        const int pos = off[col[i]] + rank[i];
        csr[pos] = (u32)(u16)r | ((u32)f2b(dis[r]) << 16);
    }
}

// ---------------- MFMA GEMM: C[M,256] = A[M,KDIM](bf16) @ BT[256,KDIM]^T ----------------
// MODE 0 (foot): Cf = gelu(acc + bias[col]); Cb = bf16(Cf)
// MODE 1 (layer): Cf[p] += acc + bias[col]  (residual RMW); Cb = bf16(Cf)
template <int KDIM, int MODE>
__global__ __launch_bounds__(256) void k_gemm_mfma(const u16* __restrict__ A,
                                                   const u16* __restrict__ BT,
                                                   const float* __restrict__ bias,
                                                   u16* __restrict__ Cb,
                                                   float* __restrict__ Cf) {
    __shared__ u16 As[64 * 64];
    __shared__ u16 Bs[256 * 64];

    const int tid = threadIdx.x;
    const int w = tid >> 6;
    const int l = tid & 63;
    const int m0 = blockIdx.x * 64;

    const int lr = l >> 3;
    const int lc = l & 7;
    const int src_slot = lc ^ lr;

    f32x4 acc[4][4] = {};

#pragma unroll
    for (int ks = 0; ks < KDIM / 64; ++ks) {
        const int k0 = ks * 64;
#pragma unroll
        for (int i = 0; i < 2; ++i) {
            const u16* asrc = A + (size_t)(m0 + 16 * w + 8 * i + lr) * KDIM + k0 + src_slot * 8;
            __builtin_amdgcn_global_load_lds(
                (const __attribute__((address_space(1))) u32*)asrc,
                (__attribute__((address_space(3))) u32*)(As + (16 * w + 8 * i) * 64), 16, 0, 0);
        }
#pragma unroll
        for (int j = 0; j < 8; ++j) {
            const u16* bsrc = BT + (size_t)(64 * w + 8 * j + lr) * KDIM + k0 + src_slot * 8;
            __builtin_amdgcn_global_load_lds(
                (const __attribute__((address_space(1))) u32*)bsrc,
                (__attribute__((address_space(3))) u32*)(Bs + (64 * w + 8 * j) * 64), 16, 0, 0);
        }
        asm volatile("s_waitcnt vmcnt(0)" ::: "memory");
        __syncthreads();

        bf16x8 a[4][2], b[4][2];
#pragma unroll
        for (int fr = 0; fr < 4; ++fr) {
            const int row = fr * 16 + (l & 15);
#pragma unroll
            for (int kk = 0; kk < 2; ++kk)
                a[fr][kk] = *reinterpret_cast<const bf16x8*>(
                    &As[row * 64 + ((kk * 4 + (l >> 4)) ^ (row & 7)) * 8]);
        }
#pragma unroll
        for (int fc = 0; fc < 4; ++fc) {
            const int row = 64 * w + fc * 16 + (l & 15);
#pragma unroll
            for (int kk = 0; kk < 2; ++kk)
                b[fc][kk] = *reinterpret_cast<const bf16x8*>(
                    &Bs[row * 64 + ((kk * 4 + (l >> 4)) ^ (row & 7)) * 8]);
        }
#pragma unroll
        for (int fr = 0; fr < 4; ++fr)
#pragma unroll
            for (int fc = 0; fc < 4; ++fc) {
                acc[fr][fc] = __builtin_amdgcn_mfma_f32_16x16x32_bf16(a[fr][0], b[fc][0], acc[fr][fc], 0, 0, 0);
                acc[fr][fc] = __builtin_amdgcn_mfma_f32_16x16x32_bf16(a[fr][1], b[fc][1], acc[fr][fc], 0, 0, 0);
            }
        __syncthreads();
    }

    const int r0 = (l >> 4) * 4;
    const int ci = l & 15;
#pragma unroll
    for (int fr = 0; fr < 4; ++fr)
#pragma unroll
        for (int fc = 0; fc < 4; ++fc) {
            const int col = w * 64 + fc * 16 + ci;
            const float bc = bias[col];
#pragma unroll
            for (int r = 0; r < 4; ++r) {
                const int row = m0 + fr * 16 + r0 + r;
                const size_t p = (size_t)row * WIDTH + col;
                if (MODE == 0) {
                    const float o = gelu_exact(acc[fr][fc][r] + bc);
                    Cf[p] = o;
                    Cb[p] = f2b(o);
                } else {
                    const float o = Cf[p] + bc + acc[fr][fc][r];
                    Cf[p] = o;
                    Cb[p] = f2b(o);
                }
            }
        }
}

// ---------------- aggregate-only: yb = bf16( Â(hb) ), channel-split, both halves one dispatch ----------------
// y_i = dis_i * ( dis_i*hb_i + sum_e ds_e*hb[src_e] ).  No h traffic, no bias.
__global__ __launch_bounds__(256) void k_aggY(const int* __restrict__ off,
                                              const u32* __restrict__ csr,
                                              const float* __restrict__ dis,
                                              const u16* __restrict__ hbin,
                                              u16* __restrict__ yb, int nbh, int N) {
    int bh = blockIdx.x;
    int ch0 = 0;
    if (bh >= nbh) { ch0 = 128; bh -= nbh; }
    const int node = (bh * 256 + threadIdx.x) >> 5;
    if (node >= N) return;
    const int hl = threadIdx.x & 31;
    const int c = ch0 + hl * 4;
    const int e0 = off[node];
    const int e1 = off[node + 1];
    const float di = dis[node];

    float acc[4];
    // self-loop
    {
        const uint2 v = *reinterpret_cast<const uint2*>(&hbin[(size_t)node * WIDTH + c]);
        acc[0] = di * b2f_lo(v.x);
        acc[1] = di * b2f_hi(v.x);
        acc[2] = di * b2f_lo(v.y);
        acc[3] = di * b2f_hi(v.y);
    }

#define EDGE_FMA(vv, dd_)                          \
    acc[0] = fmaf(dd_, b2f_lo(vv.x), acc[0]);      \
    acc[1] = fmaf(dd_, b2f_hi(vv.x), acc[1]);      \
    acc[2] = fmaf(dd_, b2f_lo(vv.y), acc[2]);      \
    acc[3] = fmaf(dd_, b2f_hi(vv.y), acc[3]);

    for (int base = e0; base < e1; base += 32) {
        const int m = min(32, e1 - base);
        u32 ep = 0;
        if (hl < m) ep = csr[base + hl];
        int j = 0;
        for (; j + 8 <= m; j += 8) {
            uint2 vv[8];
            float dd[8];
#pragma unroll
            for (int q = 0; q < 8; ++q) {
                const u32 e = (u32)__shfl((int)ep, j + q, 32);
                dd[q] = b2f_hi(e);
                vv[q] = *reinterpret_cast<const uint2*>(&hbin[(size_t)(e & 0xffffu) * WIDTH + c]);
            }
#pragma unroll
            for (int q = 0; q < 8; ++q) { EDGE_FMA(vv[q], dd[q]) }
        }
        if (j + 4 <= m) {
            uint2 vv[4];
            float dd[4];
#pragma unroll
            for (int q = 0; q < 4; ++q) {
                const u32 e = (u32)__shfl((int)ep, j + q, 32);
                dd[q] = b2f_hi(e);
                vv[q] = *reinterpret_cast<const uint2*>(&hbin[(size_t)(e & 0xffffu) * WIDTH + c]);
            }
#pragma unroll
            for (int q = 0; q < 4; ++q) { EDGE_FMA(vv[q], dd[q]) }
            j += 4;
        }
        for (; j < m; ++j) {
            const u32 e = (u32)__shfl((int)ep, j, 32);
            const float dj = b2f_hi(e);
            const uint2 v = *reinterpret_cast<const uint2*>(&hbin[(size_t)(e & 0xffffu) * WIDTH + c]);
            EDGE_FMA(v, dj)
        }
    }
#undef EDGE_FMA

    const size_t p = (size_t)node * WIDTH + c;
    uint2 ob;
    ob.x = pack2(di * acc[0], di * acc[1]);
    ob.y = pack2(di * acc[2], di * acc[3]);
    *reinterpret_cast<uint2*>(&yb[p]) = ob;
}

// ---------------- head ----------------
__global__ __launch_bounds__(256) void k_head(const float* __restrict__ h,
                                              const int* __restrict__ center,
                                              const int* __restrict__ ptr,
                                              const float* __restrict__ Wh,
                                              const float* __restrict__ bh,
                                              float* __restrict__ out) {
    __shared__ float gs[256];
    const int g = blockIdx.x;
    const int node = center[g] + ptr[g];
    gs[threadIdx.x] = gelu_exact(h[(size_t)node * WIDTH + threadIdx.x]);
    __syncthreads();
    if (threadIdx.x < 7) {
        float acc = bh[threadIdx.x];
        for (int k = 0; k < 256; ++k)
            acc = fmaf(gs[k], Wh[threadIdx.x * 256 + k], acc);
        out[g * 7 + threadIdx.x] = acc;
    }
}

extern "C" void kernel_launch(void* const* d_in, const int* in_sizes, int n_in,
                              void* d_out, int out_size, void* d_ws, size_t ws_size,
                              hipStream_t stream) {
    const float* x      = (const float*)d_in[0];
    const int*   ei     = (const int*)d_in[1];
    const int*   center = (const int*)d_in[2];
    const int*   ptr    = (const int*)d_in[3];
    const float* Wf     = (const float*)d_in[4];
    const float* bf     = (const float*)d_in[5];
    const float* Wg     = (const float*)d_in[6];
    const float* bg     = (const float*)d_in[7];
    const float* Wh     = (const float*)d_in[8];
    const float* bh     = (const float*)d_in[9];

    const int E = in_sizes[1] / 2;       // 799744
    const int N = in_sizes[0] / 64;      // 49984
    const int B = in_sizes[2];           // 32

    char* ws = (char*)d_ws;
    size_t o = 0;
    float* h       = (float*)(ws + o); o += (size_t)N * WIDTH * 4;   // 51.2 MB
    u16*   hb      = (u16*)  (ws + o); o += (size_t)N * WIDTH * 2;   // 25.6 MB
    u16*   yb      = (u16*)  (ws + o); o += (size_t)N * WIDTH * 2;   // 25.6 MB
    u16*   xb      = (u16*)  (ws + o); o += (size_t)N * 64 * 2;      // 6.4 MB
    float* dis     = (float*)(ws + o); o += (size_t)N * 4;
    int*   deg     = (int*)  (ws + o); o += (size_t)N * 4;
    int*   off     = (int*)  (ws + o); o += (size_t)(N + 1) * 4;
    int*   part    = (int*)  (ws + o); o += 1024;
    int*   rank    = (int*)  (ws + o); o += (size_t)E * 4;           // 3.2 MB
    u32*   csr     = (u32*)  (ws + o); o += (size_t)E * 4;           // 3.2 MB
    u16*   WgT     = (u16*)  (ws + o); o += (size_t)4 * 65536 * 2;   // 0.5 MB
    u16*   WfT     = (u16*)  (ws + o); o += (size_t)256 * 64 * 2;    // 32 KB

    const int* rowv = ei;
    const int* colv = ei + E;

    const int nb = (N + 255) / 256;   // 196
    const int eb = (E + 255) / 256;

    // CSR build: memset deg -> prep (weights/x/hist+rank) -> scans -> fill (no atomics)
    hipMemsetAsync(deg, 0, (size_t)N * 4, stream);
    const int total8 = N * 64 / 8;
    const int prep_threads = PREP_WG + PREP_WF + total8 + E;
    k_prep<<<(prep_threads + 255) / 256, 256, 0, stream>>>(Wg, Wf, x, colv, WgT, WfT, xb, deg, rank, total8, E);
    k_scan1<<<nb, 256, 0, stream>>>(deg, off, part, dis, N);
    k_scan3<<<nb, 256, 0, stream>>>(off, part, nb, N, E);
    k_fill<<<eb, 256, 0, stream>>>(rowv, colv, rank, dis, off, csr, E);

    // foot: h = gelu(xb @ WfT^T + bf); writes h f32 + hb bf16
    k_gemm_mfma<64, 0><<<N / 64, 256, 0, stream>>>(xb, WfT, bf, hb, h);

    // layers (swapped order): yb = Â(hb); then h += yb @ Wg[l] + bg[l], hb = bf16(h)
    const int nbh = N / 8;
    for (int l = 0; l < 4; ++l) {
        k_aggY<<<2 * nbh, 256, 0, stream>>>(off, csr, dis, hb, yb, nbh, N);
        k_gemm_mfma<256, 1><<<N / 64, 256, 0, stream>>>(yb, WgT + (size_t)l * 65536,
                                                        bg + (size_t)l * WIDTH, hb, h);
    }

    k_head<<<B, 256, 0, stream>>>(h, center, ptr, Wh, bh, (float*)d_out);
}